// Round 4
// baseline (3063.298 us; speedup 1.0000x reference)
//
#include <hip/hip_runtime.h>

#define NT 1024
#define RINGS 256

typedef _Float16 half8 __attribute__((ext_vector_type(8)));
typedef _Float16 half4 __attribute__((ext_vector_type(4)));
typedef float f32x4 __attribute__((ext_vector_type(4)));
typedef unsigned long long u64;

struct U2 { u64 a, b; };

__device__ __forceinline__ f32x4 MFMA(half8 a, half8 b, f32x4 c) {
  return __builtin_amdgcn_mfma_f32_16x16x32_f16(a, b, c, 0, 0, 0);
}
__device__ __forceinline__ float sigf(float x) {
  return __builtin_amdgcn_rcpf(1.0f + __expf(-x));
}
__device__ __forceinline__ float tanhf2(float x) {
  float ax = fabsf(x);
  float e = __expf(-2.0f * ax);
  float t = (1.0f - e) * __builtin_amdgcn_rcpf(1.0f + e);
  return copysignf(t, x);
}
__device__ __forceinline__ half8 cvt8(float4 c0, float4 c1) {
  half8 hv;
  hv[0] = (_Float16)c0.x; hv[1] = (_Float16)c0.y;
  hv[2] = (_Float16)c0.z; hv[3] = (_Float16)c0.w;
  hv[4] = (_Float16)c1.x; hv[5] = (_Float16)c1.y;
  hv[6] = (_Float16)c1.z; hv[7] = (_Float16)c1.w;
  return hv;
}
__device__ __forceinline__ half8 ldring(const _Float16* p) {
  const u64* q = (const u64*)p;
  U2 uu;
  uu.a = __hip_atomic_load(q, __ATOMIC_RELAXED, __HIP_MEMORY_SCOPE_AGENT);
  uu.b = __hip_atomic_load(q + 1, __ATOMIC_RELAXED, __HIP_MEMORY_SCOPE_AGENT);
  return __builtin_bit_cast(half8, uu);
}
__device__ __forceinline__ unsigned wpoll(unsigned* p, unsigned tgt,
                                          unsigned cached, int l) {
  unsigned c = cached;
  while (c < tgt) {
    unsigned pv = 0;
    if (l == 0)
      pv = __hip_atomic_load(p, __ATOMIC_ACQUIRE, __HIP_MEMORY_SCOPE_AGENT);
    c = (unsigned)__builtin_amdgcn_readfirstlane((int)pv);
    if (c < tgt) __builtin_amdgcn_s_sleep(2);
  }
  return c;
}

// Repack x [B,T,64] f32 -> f16 B-fragments Xf[g][t][kt][lane][8]
// k-perm within tile: kk(lane,j) = (j>>2)*16 + (lane>>4)*4 + (j&3)
__global__ __launch_bounds__(256) void prep_x(const float* __restrict__ x,
                                              _Float16* __restrict__ Xf) {
  int t0 = blockIdx.x * 256 + threadIdx.x;
  int l = t0 & 63;
  int fid = t0 >> 6;                  // ((g*NT + t)*2 + kt)
  int kt = fid & 1;
  int t = (fid >> 1) & (NT - 1);
  int g = fid >> 11;
  int bt = g * 16 + (l & 15);
  int kb = kt * 32 + (l >> 4) * 4;
  const float* src = x + ((size_t)bt * NT + (size_t)t) * 64 + kb;
  float4 v0 = *(const float4*)src;
  float4 v1 = *(const float4*)(src + 16);
  *(half8*)(Xf + (size_t)fid * 512 + l * 8) = cvt8(v0, v1);
}

// 32 blocks x 256 threads. role = bid>>3: 0=L0a(h0 rows 0-63), 1=L0b(64-127),
// 2=L1a(h1 rows 0-63), 3=L1b(64-127, +FC). g = bid&7 (batch group of 16).
// Each block: wave w owns M-tile quartet rows base+16w (i,f,g,o lane-local,
// C layout col=lane&15, row=(lane>>4)*4+reg). Own h-half frags via LDS;
// remote half via agent-scope ring/exchange; L0->L1 via 256-slot h0 ring.
__global__ __launch_bounds__(256, 1) void lstm_main(
    const float* __restrict__ wih0, const float* __restrict__ whh0,
    const float* __restrict__ wih1, const float* __restrict__ whh1,
    const float* __restrict__ bih, const float* __restrict__ bhh,
    const float* __restrict__ fcw, const float* __restrict__ fcb,
    const _Float16* __restrict__ Xf, _Float16* __restrict__ ringH0,
    _Float16* __restrict__ h1x, unsigned* __restrict__ flags,
    float* __restrict__ out) {
  const int tid = threadIdx.x;
  const int w = tid >> 6, l = tid & 63;
  const int n = l & 15, lg = l >> 4;
  const int role = blockIdx.x >> 3;
  const int g = blockIdx.x & 7;
  const int half = role & 1;

  __shared__ _Float16 hfr[2][2][64][8];  // own-half frag 2-slot ring (4 KB)
  if (tid < 128) {
    half8 z = {0, 0, 0, 0, 0, 0, 0, 0};
    ((half8*)&hfr[1][0][0][0])[tid] = z;  // h_{-1} = 0 (slot 1)
  }
  _Float16* ringG = ringH0 + (size_t)g * RINGS * 2048;
  unsigned* fl = flags;
#define FLAGP(st) (fl + ((st) * 8 + g) * 16)

  const half8 hz = {0, 0, 0, 0, 0, 0, 0, 0};

  if (role < 2) {
    // =========================== layer-0 half ===========================
    half8 A[4][6];
    f32x4 bias[4];
#pragma unroll
    for (int q = 0; q < 4; ++q) {
      int row = ((q << 3) + (half << 2) + w) * 16 + n;
#pragma unroll
      for (int kt = 0; kt < 2; ++kt) {
        const float* wp = wih0 + (size_t)row * 64 + kt * 32 + lg * 4;
        A[q][kt] = cvt8(*(const float4*)wp, *(const float4*)(wp + 16));
      }
#pragma unroll
      for (int kt = 0; kt < 4; ++kt) {
        const float* wp = whh0 + (size_t)row * 128 + kt * 32 + lg * 4;
        A[q][2 + kt] = cvt8(*(const float4*)wp, *(const float4*)(wp + 16));
      }
      int rb = ((q << 3) + (half << 2) + w) * 16 + lg * 4;
      f32x4 bv;
#pragma unroll
      for (int r = 0; r < 4; ++r) bv[r] = bih[rb + r] + bhh[rb + r];
      bias[q] = bv;
    }
    unsigned* progSelf = FLAGP(half);
    unsigned* progSib = FLAGP(half ^ 1);
    unsigned* consA = FLAGP(2);
    unsigned* consB = FLAGP(3);
    const int ownK = half << 1;        // ring kt of own half
    const int remK = (half ^ 1) << 1;
    const _Float16* XfG = Xf + (size_t)g * NT * 1024;
    half8 x0 = *(const half8*)(XfG + l * 8);
    half8 x1 = *(const half8*)(XfG + 512 + l * 8);
    half8 h0r0 = hz, h0r1 = hz;        // remote half of h0[s-1]
    f32x4 cst = {0.f, 0.f, 0.f, 0.f};
    unsigned PcS = 0, PcA = 0, PcB = 0;
    __syncthreads();
    for (int s = 0; s < NT; ++s) {
      half8 xn0, xn1;
      if (s + 1 < NT) {
        const _Float16* p = XfG + (size_t)(s + 1) * 1024 + l * 8;
        xn0 = *(const half8*)p;
        xn1 = *(const half8*)(p + 512);
      }
      if ((s & 31) == 0 && s >= RINGS - 64) {  // ring backpressure
        unsigned tgt = (unsigned)(s - (RINGS - 64)) + 1;
        PcA = wpoll(consA, tgt, PcA, l);
        PcB = wpoll(consB, tgt, PcB, l);
      }
      half8 bo0 = *(const half8*)&hfr[(s + 1) & 1][0][l][0];  // own h0[s-1]
      half8 bo1 = *(const half8*)&hfr[(s + 1) & 1][1][l][0];
      half8 b2 = (half == 0) ? bo0 : h0r0;   // h0 kt0
      half8 b3 = (half == 0) ? bo1 : h0r1;   // h0 kt1
      half8 b4 = (half == 0) ? h0r0 : bo0;   // h0 kt2
      half8 b5 = (half == 0) ? h0r1 : bo1;   // h0 kt3
      f32x4 acc[4];
#pragma unroll
      for (int q = 0; q < 4; ++q) {
        f32x4 a = bias[q];
        a = MFMA(A[q][0], x0, a);
        a = MFMA(A[q][1], x1, a);
        a = MFMA(A[q][2], b2, a);
        a = MFMA(A[q][3], b3, a);
        a = MFMA(A[q][4], b4, a);
        a = MFMA(A[q][5], b5, a);
        acc[q] = a;
      }
      half4 hh;
#pragma unroll
      for (int r = 0; r < 4; ++r) {
        float iv = sigf(acc[0][r]), fv = sigf(acc[1][r]);
        float gv = tanhf2(acc[2][r]), ov = sigf(acc[3][r]);
        cst[r] = fv * cst[r] + iv * gv;
        hh[r] = (_Float16)(ov * tanhf2(cst[r]));
      }
      *(half4*)&hfr[s & 1][w >> 1][l][(w & 1) << 2] = hh;
      u64 uh = __builtin_bit_cast(u64, hh);
      __hip_atomic_store(
          (u64*)(ringG + (size_t)(s & (RINGS - 1)) * 2048 +
                 (ownK + (w >> 1)) * 512 + l * 8 + (w & 1) * 4),
          uh, __ATOMIC_RELAXED, __HIP_MEMORY_SCOPE_AGENT);
      __syncthreads();  // drains vmcnt; all waves' ring stores done
      if (tid == 0)
        __hip_atomic_store(progSelf, (unsigned)(s + 1), __ATOMIC_RELEASE,
                           __HIP_MEMORY_SCOPE_AGENT);
      if (s + 1 < NT) {  // fetch sibling's half of h0[s]
        PcS = wpoll(progSib, (unsigned)(s + 1), PcS, l);
        const _Float16* rb2 =
            ringG + (size_t)(s & (RINGS - 1)) * 2048 + remK * 512 + l * 8;
        h0r0 = ldring(rb2);
        h0r1 = ldring(rb2 + 512);
        x0 = xn0;
        x1 = xn1;
      }
    }
  } else {
    // ======================= layer-1 half (+FC on b) =======================
    half8 A[4][8], FCA[4];
    f32x4 bias[4], fcbv = {0.f, 0.f, 0.f, 0.f};
#pragma unroll
    for (int q = 0; q < 4; ++q) {
      int row = ((q << 3) + (half << 2) + w) * 16 + n;
#pragma unroll
      for (int kt = 0; kt < 4; ++kt) {
        const float* wp = wih1 + (size_t)row * 128 + kt * 32 + lg * 4;
        A[q][kt] = cvt8(*(const float4*)wp, *(const float4*)(wp + 16));
      }
#pragma unroll
      for (int kt = 0; kt < 4; ++kt) {
        const float* wp = whh1 + (size_t)row * 128 + kt * 32 + lg * 4;
        A[q][4 + kt] = cvt8(*(const float4*)wp, *(const float4*)(wp + 16));
      }
      int rb = ((q << 3) + (half << 2) + w) * 16 + lg * 4;
      f32x4 bv;
#pragma unroll
      for (int r = 0; r < 4; ++r)
        bv[r] = bih[512 + rb + r] + bhh[512 + rb + r];
      bias[q] = bv;
    }
    if (half == 1) {
      int frow = (w << 4) + n;
#pragma unroll
      for (int kt = 0; kt < 4; ++kt) {
        const float* wp = fcw + (size_t)frow * 128 + kt * 32 + lg * 4;
        FCA[kt] = cvt8(*(const float4*)wp, *(const float4*)(wp + 16));
      }
      fcbv = *(const f32x4*)(fcb + (w << 4) + lg * 4);
    }
    unsigned* progSelf = FLAGP(2 + half);
    unsigned* progSib = FLAGP(2 + (half ^ 1));
    unsigned* pL0a = FLAGP(0);
    unsigned* pL0b = FLAGP(1);
    _Float16* sx = h1x + (size_t)((half << 3) + g) * 4096;        // self out
    _Float16* rx = h1x + (size_t)(((half ^ 1) << 3) + g) * 4096;  // sib in
    unsigned PcS = 0, PcA = 0, PcB = 0;
    PcA = wpoll(pL0a, 1, 0, l);
    PcB = wpoll(pL0b, 1, 0, l);
    half8 h0c0 = ldring(ringG + l * 8);          // h0[0] frags
    half8 h0c1 = ldring(ringG + 512 + l * 8);
    half8 h0c2 = ldring(ringG + 1024 + l * 8);
    half8 h0c3 = ldring(ringG + 1536 + l * 8);
    half8 h1r0 = hz, h1r1 = hz;                  // remote half of h1[t-1]
    f32x4 cst = {0.f, 0.f, 0.f, 0.f};
    float* outG = out + (size_t)((g << 4) + n) * NT * 64 + (w << 4) + lg * 4;
    __syncthreads();
    for (int t = 0; t <= NT; ++t) {
      half8 bo0 = *(const half8*)&hfr[(t + 1) & 1][0][l][0];  // own h1[t-1]
      half8 bo1 = *(const half8*)&hfr[(t + 1) & 1][1][l][0];
      f32x4 acc[4];
      if (t < NT) {
        half8 b4 = (half == 0) ? bo0 : h1r0;   // h1 kt0
        half8 b5 = (half == 0) ? bo1 : h1r1;   // h1 kt1
        half8 b6 = (half == 0) ? h1r0 : bo0;   // h1 kt2
        half8 b7 = (half == 0) ? h1r1 : bo1;   // h1 kt3
#pragma unroll
        for (int q = 0; q < 4; ++q) {
          f32x4 a = bias[q];
          a = MFMA(A[q][0], h0c0, a);
          a = MFMA(A[q][1], h0c1, a);
          a = MFMA(A[q][2], h0c2, a);
          a = MFMA(A[q][3], h0c3, a);
          a = MFMA(A[q][4], b4, a);
          a = MFMA(A[q][5], b5, a);
          a = MFMA(A[q][6], b6, a);
          a = MFMA(A[q][7], b7, a);
          acc[q] = a;
        }
      }
      if (half == 1 && t >= 1) {  // FC of h1[t-1]: kt0,1 remote; kt2,3 own
        f32x4 afc = fcbv;
        afc = MFMA(FCA[0], h1r0, afc);
        afc = MFMA(FCA[1], h1r1, afc);
        afc = MFMA(FCA[2], bo0, afc);
        afc = MFMA(FCA[3], bo1, afc);
        *(f32x4*)(outG + (size_t)(t - 1) * 64) = afc;
      }
      half8 h0n0, h0n1, h0n2, h0n3;
      if (t + 1 < NT) {  // prefetch h0[t+1] (producer far ahead; poll cached)
        if (PcA < (unsigned)(t + 2)) PcA = wpoll(pL0a, t + 2, PcA, l);
        if (PcB < (unsigned)(t + 2)) PcB = wpoll(pL0b, t + 2, PcB, l);
        const _Float16* rb2 =
            ringG + (size_t)((t + 1) & (RINGS - 1)) * 2048 + l * 8;
        h0n0 = ldring(rb2);
        h0n1 = ldring(rb2 + 512);
        h0n2 = ldring(rb2 + 1024);
        h0n3 = ldring(rb2 + 1536);
      }
      if (t < NT) {
        half4 hh;
#pragma unroll
        for (int r = 0; r < 4; ++r) {
          float iv = sigf(acc[0][r]), fv = sigf(acc[1][r]);
          float gv = tanhf2(acc[2][r]), ov = sigf(acc[3][r]);
          cst[r] = fv * cst[r] + iv * gv;
          hh[r] = (_Float16)(ov * tanhf2(cst[r]));
        }
        *(half4*)&hfr[t & 1][w >> 1][l][(w & 1) << 2] = hh;
        u64 uh = __builtin_bit_cast(u64, hh);
        __hip_atomic_store((u64*)(sx + (size_t)(t & 3) * 1024 +
                                  (w >> 1) * 512 + l * 8 + (w & 1) * 4),
                           uh, __ATOMIC_RELAXED, __HIP_MEMORY_SCOPE_AGENT);
      }
      __syncthreads();
      if (tid == 0)
        __hip_atomic_store(progSelf, (unsigned)(t + 1), __ATOMIC_RELEASE,
                           __HIP_MEMORY_SCOPE_AGENT);
      if (t < NT) {  // fetch sibling's half of h1[t]
        PcS = wpoll(progSib, (unsigned)(t + 1), PcS, l);
        const _Float16* xb = rx + (size_t)(t & 3) * 1024 + l * 8;
        h1r0 = ldring(xb);
        h1r1 = ldring(xb + 512);
      }
      if (t + 1 < NT) {
        h0c0 = h0n0; h0c1 = h0n1; h0c2 = h0n2; h0c3 = h0n3;
      }
    }
  }
#undef FLAGP
}

extern "C" void kernel_launch(void* const* d_in, const int* in_sizes, int n_in,
                              void* d_out, int out_size, void* d_ws, size_t ws_size,
                              hipStream_t stream) {
  const float* x     = (const float*)d_in[0];
  const float* w_ih0 = (const float*)d_in[1];
  const float* w_hh0 = (const float*)d_in[2];
  const float* w_ih1 = (const float*)d_in[3];
  const float* w_hh1 = (const float*)d_in[4];
  const float* b_ih  = (const float*)d_in[5];
  const float* b_hh  = (const float*)d_in[6];
  const float* fc_w  = (const float*)d_in[7];
  const float* fc_b  = (const float*)d_in[8];

  _Float16* Xf   = (_Float16*)d_ws;                                   // 16 MB
  _Float16* ring = (_Float16*)((char*)d_ws + (16u << 20));            // 8 MB
  _Float16* h1x  = (_Float16*)((char*)d_ws + (24u << 20));            // 128 KB
  unsigned* flags = (unsigned*)((char*)d_ws + (24u << 20) + (256u << 10));

  hipMemsetAsync(flags, 0, 4096, stream);
  prep_x<<<4096, 256, 0, stream>>>(x, Xf);
  lstm_main<<<32, 256, 0, stream>>>(w_ih0, w_hh0, w_ih1, w_hh1, b_ih, b_hh,
                                    fc_w, fc_b, Xf, ring, h1x, flags,
                                    (float*)d_out);
}

// Round 5
// 1521.666 us; speedup vs baseline: 2.0131x; 2.0131x over previous
//
#include <hip/hip_runtime.h>

#define NT 1024
#define RINGS 256

typedef _Float16 half8 __attribute__((ext_vector_type(8)));
typedef _Float16 half4 __attribute__((ext_vector_type(4)));
typedef float f32x4 __attribute__((ext_vector_type(4)));
typedef unsigned long long u64;
struct U2 { u64 a, b; };

__device__ __forceinline__ f32x4 MFMA(half8 a, half8 b, f32x4 c) {
  return __builtin_amdgcn_mfma_f32_16x16x32_f16(a, b, c, 0, 0, 0);
}
__device__ __forceinline__ float sigf(float x) {
  return __builtin_amdgcn_rcpf(1.0f + __expf(-x));
}
__device__ __forceinline__ float tanhf2(float x) {
  float ax = fabsf(x);
  float e = __expf(-2.0f * ax);
  float t = (1.0f - e) * __builtin_amdgcn_rcpf(1.0f + e);
  return copysignf(t, x);
}
__device__ __forceinline__ half8 cvt8(float4 c0, float4 c1) {
  half8 hv;
  hv[0] = (_Float16)c0.x; hv[1] = (_Float16)c0.y;
  hv[2] = (_Float16)c0.z; hv[3] = (_Float16)c0.w;
  hv[4] = (_Float16)c1.x; hv[5] = (_Float16)c1.y;
  hv[6] = (_Float16)c1.z; hv[7] = (_Float16)c1.w;
  return hv;
}
__device__ __forceinline__ half8 ldring(const _Float16* p) {
  const u64* q = (const u64*)p;
  U2 uu;
  uu.a = __hip_atomic_load(q, __ATOMIC_RELAXED, __HIP_MEMORY_SCOPE_AGENT);
  uu.b = __hip_atomic_load(q + 1, __ATOMIC_RELAXED, __HIP_MEMORY_SCOPE_AGENT);
  return __builtin_bit_cast(half8, uu);
}
__device__ __forceinline__ unsigned wpoll(unsigned* p, unsigned tgt,
                                          unsigned cached, int l) {
  unsigned c = cached;
  while (c < tgt) {
    unsigned pv = 0;
    if (l == 0)
      pv = __hip_atomic_load(p, __ATOMIC_ACQUIRE, __HIP_MEMORY_SCOPE_AGENT);
    c = (unsigned)__builtin_amdgcn_readfirstlane((int)pv);
    if (c < tgt) __builtin_amdgcn_s_sleep(2);
  }
  return c;
}

// Repack x [B,T,64] f32 -> f16 B-fragments Xf[g][t][kt][lane][8]
// k-perm within tile: kk(lane,j) = (j>>2)*16 + (lane>>4)*4 + (j&3)
__global__ __launch_bounds__(256) void prep_x(const float* __restrict__ x,
                                              _Float16* __restrict__ Xf) {
  int t0 = blockIdx.x * 256 + threadIdx.x;
  int l = t0 & 63;
  int fid = t0 >> 6;                  // ((g*NT + t)*2 + kt)
  int kt = fid & 1;
  int t = (fid >> 1) & (NT - 1);
  int g = fid >> 11;
  int bt = g * 16 + (l & 15);
  int kb = kt * 32 + (l >> 4) * 4;
  const float* src = x + ((size_t)bt * NT + (size_t)t) * 64 + kb;
  float4 v0 = *(const float4*)src;
  float4 v1 = *(const float4*)(src + 16);
  *(half8*)(Xf + (size_t)fid * 512 + l * 8) = cvt8(v0, v1);
}

// 16 blocks x 512 threads. Blocks 0-7: layer-0 producer for batch group g
// (16 batch rows). Blocks 8-15: layer-1 + FC consumer for group g.
// Wave w owns M-tiles {w+8q} -> i,f,g,o of row w*16+lg*4+r are lane-local
// (C layout col=lane&15, row=(lane>>4)*4+reg [m89/m91]). h frags self-lane
// via LDS; L0->L1 via 256-slot agent-scope ring, publish AFTER barrier
// (drain already done), store EARLY next step (ack hidden under MFMAs).
__global__ __launch_bounds__(512, 1) void lstm_main(
    const float* __restrict__ wih0, const float* __restrict__ whh0,
    const float* __restrict__ wih1, const float* __restrict__ whh1,
    const float* __restrict__ bih, const float* __restrict__ bhh,
    const float* __restrict__ fcw, const float* __restrict__ fcb,
    const _Float16* __restrict__ Xf, _Float16* __restrict__ ringH0,
    unsigned* __restrict__ flags, float* __restrict__ out) {
  const int tid = threadIdx.x;
  const int w = tid >> 6, l = tid & 63;
  const int n = l & 15, lg = l >> 4;
  const bool producer = blockIdx.x < 8;
  const int g = blockIdx.x & 7;

  __shared__ _Float16 hfr[2][4][64][8];   // own-layer h frag ring (8 KB)
  __shared__ _Float16 fcl[4][4][64][8];   // FC A-frags per FC wave (16 KB)

  _Float16* ringG = ringH0 + (size_t)g * RINGS * 2048;
  unsigned* prog = flags + g * 16;        // producer progress
  unsigned* cons = flags + (8 + g) * 16;  // consumer progress
  const half8 hz = {0, 0, 0, 0, 0, 0, 0, 0};

  if (producer) {
    // ---- layer-0: Z = [x(64); h0(128)], 6 K-tiles ----
    half8 A[4][6];
    f32x4 bias[4];
#pragma unroll
    for (int q = 0; q < 4; ++q) {
      int row = (w + 8 * q) * 16 + n;
#pragma unroll
      for (int kt = 0; kt < 2; ++kt) {
        const float* wp = wih0 + (size_t)row * 64 + kt * 32 + lg * 4;
        A[q][kt] = cvt8(*(const float4*)wp, *(const float4*)(wp + 16));
      }
#pragma unroll
      for (int kt = 0; kt < 4; ++kt) {
        const float* wp = whh0 + (size_t)row * 128 + kt * 32 + lg * 4;
        A[q][2 + kt] = cvt8(*(const float4*)wp, *(const float4*)(wp + 16));
      }
      int rb = (w + 8 * q) * 16 + lg * 4;
      f32x4 bv;
#pragma unroll
      for (int r = 0; r < 4; ++r) bv[r] = bih[rb + r] + bhh[rb + r];
      bias[q] = bv;
    }
    if (tid < 256) ((half8*)&hfr[1][0][0][0])[tid] = hz;  // h0[-1]=0
    const _Float16* XfG = Xf + (size_t)g * NT * 1024;
    half8 x0 = *(const half8*)(XfG + l * 8);
    half8 x1 = *(const half8*)(XfG + 512 + l * 8);
    f32x4 cst = {0.f, 0.f, 0.f, 0.f};
    half4 hh = {0, 0, 0, 0};
    unsigned Cc = 0;
    __syncthreads();
    for (int s = 0; s < NT; ++s) {
      if (s >= 1) {  // EARLY ring store of h0[s-1]; acked long before barrier
        u64 uh = __builtin_bit_cast(u64, hh);
        __hip_atomic_store(
            (u64*)(ringG + (size_t)((s - 1) & (RINGS - 1)) * 2048 +
                   (w >> 1) * 512 + l * 8 + (w & 1) * 4),
            uh, __ATOMIC_RELAXED, __HIP_MEMORY_SCOPE_AGENT);
      }
      half8 xn0, xn1;
      if (s + 1 < NT) {
        const _Float16* p = XfG + (size_t)(s + 1) * 1024 + l * 8;
        xn0 = *(const half8*)p;
        xn1 = *(const half8*)(p + 512);
      }
      if (s >= 200 && (s & 31) == 0)  // ring backpressure (192-slot lead cap)
        Cc = wpoll(cons, (unsigned)(s - 192), Cc, l);
      const int rdk = (s + 1) & 1;
      half8 b2 = *(const half8*)&hfr[rdk][0][l][0];
      half8 b3 = *(const half8*)&hfr[rdk][1][l][0];
      half8 b4 = *(const half8*)&hfr[rdk][2][l][0];
      half8 b5 = *(const half8*)&hfr[rdk][3][l][0];
      f32x4 acc0 = bias[0], acc1 = bias[1], acc2 = bias[2], acc3 = bias[3];
      acc0 = MFMA(A[0][0], x0, acc0); acc1 = MFMA(A[1][0], x0, acc1);
      acc2 = MFMA(A[2][0], x0, acc2); acc3 = MFMA(A[3][0], x0, acc3);
      acc0 = MFMA(A[0][1], x1, acc0); acc1 = MFMA(A[1][1], x1, acc1);
      acc2 = MFMA(A[2][1], x1, acc2); acc3 = MFMA(A[3][1], x1, acc3);
      acc0 = MFMA(A[0][2], b2, acc0); acc1 = MFMA(A[1][2], b2, acc1);
      acc2 = MFMA(A[2][2], b2, acc2); acc3 = MFMA(A[3][2], b2, acc3);
      acc0 = MFMA(A[0][3], b3, acc0); acc1 = MFMA(A[1][3], b3, acc1);
      acc2 = MFMA(A[2][3], b3, acc2); acc3 = MFMA(A[3][3], b3, acc3);
      acc0 = MFMA(A[0][4], b4, acc0); acc1 = MFMA(A[1][4], b4, acc1);
      acc2 = MFMA(A[2][4], b4, acc2); acc3 = MFMA(A[3][4], b4, acc3);
      acc0 = MFMA(A[0][5], b5, acc0); acc1 = MFMA(A[1][5], b5, acc1);
      acc2 = MFMA(A[2][5], b5, acc2); acc3 = MFMA(A[3][5], b5, acc3);
#pragma unroll
      for (int r = 0; r < 4; ++r) {
        float iv = sigf(acc0[r]), fv = sigf(acc1[r]);
        float gv = tanhf2(acc2[r]), ov = sigf(acc3[r]);
        cst[r] = fv * cst[r] + iv * gv;
        hh[r] = (_Float16)(ov * tanhf2(cst[r]));
      }
      *(half4*)&hfr[s & 1][w >> 1][l][(w & 1) << 2] = hh;
      __syncthreads();  // drains lds + the (old) ring store
      if (tid == 0)     // entries [0..s-1] now globally visible
        __hip_atomic_store(prog, (unsigned)s, __ATOMIC_RELEASE,
                           __HIP_MEMORY_SCOPE_AGENT);
      x0 = xn0;
      x1 = xn1;
    }
    {  // final entry NT-1
      u64 uh = __builtin_bit_cast(u64, hh);
      __hip_atomic_store(
          (u64*)(ringG + (size_t)((NT - 1) & (RINGS - 1)) * 2048 +
                 (w >> 1) * 512 + l * 8 + (w & 1) * 4),
          uh, __ATOMIC_RELAXED, __HIP_MEMORY_SCOPE_AGENT);
    }
    __syncthreads();
    if (tid == 0)
      __hip_atomic_store(prog, (unsigned)NT, __ATOMIC_RELEASE,
                         __HIP_MEMORY_SCOPE_AGENT);
  } else {
    // ---- layer-1 + FC: Z = [h0(128); h1(128)], 8 K-tiles ----
    half8 A[4][8];
    f32x4 bias[4], fcbv = {0.f, 0.f, 0.f, 0.f};
#pragma unroll
    for (int q = 0; q < 4; ++q) {
      int row = (w + 8 * q) * 16 + n;
#pragma unroll
      for (int kt = 0; kt < 4; ++kt) {
        const float* wp = wih1 + (size_t)row * 128 + kt * 32 + lg * 4;
        A[q][kt] = cvt8(*(const float4*)wp, *(const float4*)(wp + 16));
      }
#pragma unroll
      for (int kt = 0; kt < 4; ++kt) {
        const float* wp = whh1 + (size_t)row * 128 + kt * 32 + lg * 4;
        A[q][4 + kt] = cvt8(*(const float4*)wp, *(const float4*)(wp + 16));
      }
      int rb = (w + 8 * q) * 16 + lg * 4;
      f32x4 bv;
#pragma unroll
      for (int r = 0; r < 4; ++r)
        bv[r] = bih[512 + rb + r] + bhh[512 + rb + r];
      bias[q] = bv;
    }
    if (w < 4) {  // FC A-frags -> LDS (per FC wave w: out M-tile w)
      int frow = (w << 4) + n;
#pragma unroll
      for (int kt = 0; kt < 4; ++kt) {
        const float* wp = fcw + (size_t)frow * 128 + kt * 32 + lg * 4;
        *(half8*)&fcl[w][kt][l][0] =
            cvt8(*(const float4*)wp, *(const float4*)(wp + 16));
      }
      fcbv = *(const f32x4*)(fcb + (w << 4) + lg * 4);
    }
    if (tid < 256) ((half8*)&hfr[1][0][0][0])[tid] = hz;  // h1[-1]=0
    float* outG = out + (size_t)((g << 4) + n) * NT * 64 + (w << 4) + lg * 4;
    f32x4 cst = {0.f, 0.f, 0.f, 0.f};
    __syncthreads();
    unsigned Pc = wpoll(prog, 2u, 0u, l);
    half8 hA0 = ldring(ringG + l * 8);
    half8 hA1 = ldring(ringG + 512 + l * 8);
    half8 hA2 = ldring(ringG + 1024 + l * 8);
    half8 hA3 = ldring(ringG + 1536 + l * 8);
    const _Float16* rb1 = ringG + 2048 + l * 8;
    half8 hB0 = ldring(rb1);
    half8 hB1 = ldring(rb1 + 512);
    half8 hB2 = ldring(rb1 + 1024);
    half8 hB3 = ldring(rb1 + 1536);

#define CSTEP(T, C0, C1, C2, C3)                                               \
  {                                                                            \
    const int rdk_ = ((T) + 1) & 1;                                            \
    half8 b4 = *(const half8*)&hfr[rdk_][0][l][0];                             \
    half8 b5 = *(const half8*)&hfr[rdk_][1][l][0];                             \
    half8 b6 = *(const half8*)&hfr[rdk_][2][l][0];                             \
    half8 b7 = *(const half8*)&hfr[rdk_][3][l][0];                             \
    f32x4 acc0 = bias[0], acc1 = bias[1], acc2 = bias[2], acc3 = bias[3];      \
    acc0 = MFMA(A[0][0], C0, acc0); acc1 = MFMA(A[1][0], C0, acc1);            \
    acc2 = MFMA(A[2][0], C0, acc2); acc3 = MFMA(A[3][0], C0, acc3);            \
    acc0 = MFMA(A[0][1], C1, acc0); acc1 = MFMA(A[1][1], C1, acc1);            \
    acc2 = MFMA(A[2][1], C1, acc2); acc3 = MFMA(A[3][1], C1, acc3);            \
    acc0 = MFMA(A[0][2], C2, acc0); acc1 = MFMA(A[1][2], C2, acc1);            \
    acc2 = MFMA(A[2][2], C2, acc2); acc3 = MFMA(A[3][2], C2, acc3);            \
    acc0 = MFMA(A[0][3], C3, acc0); acc1 = MFMA(A[1][3], C3, acc1);            \
    acc2 = MFMA(A[2][3], C3, acc2); acc3 = MFMA(A[3][3], C3, acc3);            \
    if ((T) + 2 < NT) { /* reload CUR with h0[T+2]; flies across barriers */   \
      Pc = wpoll(prog, (unsigned)((T) + 3), Pc, l);                            \
      const _Float16* rb_ =                                                    \
          ringG + (size_t)(((T) + 2) & (RINGS - 1)) * 2048 + l * 8;            \
      C0 = ldring(rb_);        C1 = ldring(rb_ + 512);                         \
      C2 = ldring(rb_ + 1024); C3 = ldring(rb_ + 1536);                        \
    }                                                                          \
    acc0 = MFMA(A[0][4], b4, acc0); acc1 = MFMA(A[1][4], b4, acc1);            \
    acc2 = MFMA(A[2][4], b4, acc2); acc3 = MFMA(A[3][4], b4, acc3);            \
    acc0 = MFMA(A[0][5], b5, acc0); acc1 = MFMA(A[1][5], b5, acc1);            \
    acc2 = MFMA(A[2][5], b5, acc2); acc3 = MFMA(A[3][5], b5, acc3);            \
    acc0 = MFMA(A[0][6], b6, acc0); acc1 = MFMA(A[1][6], b6, acc1);            \
    acc2 = MFMA(A[2][6], b6, acc2); acc3 = MFMA(A[3][6], b6, acc3);            \
    acc0 = MFMA(A[0][7], b7, acc0); acc1 = MFMA(A[1][7], b7, acc1);            \
    acc2 = MFMA(A[2][7], b7, acc2); acc3 = MFMA(A[3][7], b7, acc3);            \
    if (w < 4) { /* FC of h1[T-1] on same operands */                          \
      half8 f0 = *(const half8*)&fcl[w][0][l][0];                              \
      half8 f1 = *(const half8*)&fcl[w][1][l][0];                              \
      half8 f2 = *(const half8*)&fcl[w][2][l][0];                              \
      half8 f3 = *(const half8*)&fcl[w][3][l][0];                              \
      f32x4 afc = fcbv;                                                        \
      afc = MFMA(f0, b4, afc); afc = MFMA(f1, b5, afc);                        \
      afc = MFMA(f2, b6, afc); afc = MFMA(f3, b7, afc);                        \
      if ((T) >= 1) *(f32x4*)(outG + (size_t)((T) - 1) * 64) = afc;            \
    }                                                                          \
    half4 hh;                                                                  \
    _Pragma("unroll")                                                          \
    for (int r = 0; r < 4; ++r) {                                              \
      float iv = sigf(acc0[r]), fv = sigf(acc1[r]);                            \
      float gv = tanhf2(acc2[r]), ov = sigf(acc3[r]);                          \
      cst[r] = fv * cst[r] + iv * gv;                                          \
      hh[r] = (_Float16)(ov * tanhf2(cst[r]));                                 \
    }                                                                          \
    *(half4*)&hfr[(T) & 1][w >> 1][l][(w & 1) << 2] = hh;                      \
    if (tid == 0 && ((T) & 31) == 0)                                           \
      __hip_atomic_store(cons, (unsigned)(T), __ATOMIC_RELAXED,                \
                         __HIP_MEMORY_SCOPE_AGENT);                            \
    asm volatile("s_waitcnt lgkmcnt(0)" ::: "memory");                         \
    __builtin_amdgcn_sched_barrier(0);                                         \
    __builtin_amdgcn_s_barrier(); /* raw: h0 prefetch stays in flight */       \
    __builtin_amdgcn_sched_barrier(0);                                         \
  }

    for (int t = 0; t < NT; t += 2) {
      CSTEP(t, hA0, hA1, hA2, hA3);
      CSTEP(t + 1, hB0, hB1, hB2, hB3);
    }
#undef CSTEP
    {  // epilogue: FC of h1[NT-1] -> out[NT-1]
      half8 b4 = *(const half8*)&hfr[(NT + 1) & 1][0][l][0];
      half8 b5 = *(const half8*)&hfr[(NT + 1) & 1][1][l][0];
      half8 b6 = *(const half8*)&hfr[(NT + 1) & 1][2][l][0];
      half8 b7 = *(const half8*)&hfr[(NT + 1) & 1][3][l][0];
      if (w < 4) {
        half8 f0 = *(const half8*)&fcl[w][0][l][0];
        half8 f1 = *(const half8*)&fcl[w][1][l][0];
        half8 f2 = *(const half8*)&fcl[w][2][l][0];
        half8 f3 = *(const half8*)&fcl[w][3][l][0];
        f32x4 afc = fcbv;
        afc = MFMA(f0, b4, afc); afc = MFMA(f1, b5, afc);
        afc = MFMA(f2, b6, afc); afc = MFMA(f3, b7, afc);
        *(f32x4*)(outG + (size_t)(NT - 1) * 64) = afc;
      }
    }
  }
}

extern "C" void kernel_launch(void* const* d_in, const int* in_sizes, int n_in,
                              void* d_out, int out_size, void* d_ws, size_t ws_size,
                              hipStream_t stream) {
  const float* x     = (const float*)d_in[0];
  const float* w_ih0 = (const float*)d_in[1];
  const float* w_hh0 = (const float*)d_in[2];
  const float* w_ih1 = (const float*)d_in[3];
  const float* w_hh1 = (const float*)d_in[4];
  const float* b_ih  = (const float*)d_in[5];
  const float* b_hh  = (const float*)d_in[6];
  const float* fc_w  = (const float*)d_in[7];
  const float* fc_b  = (const float*)d_in[8];

  _Float16* Xf   = (_Float16*)d_ws;                           // 16 MB
  _Float16* ring = (_Float16*)((char*)d_ws + (16u << 20));    // 8 MB
  unsigned* flags = (unsigned*)((char*)d_ws + (24u << 20));   // 4 KB

  hipMemsetAsync(flags, 0, 4096, stream);
  prep_x<<<4096, 256, 0, stream>>>(x, Xf);
  lstm_main<<<16, 512, 0, stream>>>(w_ih0, w_hh0, w_ih1, w_hh1, b_ih, b_hh,
                                    fc_w, fc_b, Xf, ring, flags,
                                    (float*)d_out);
}

// Round 6
// 1324.280 us; speedup vs baseline: 2.3132x; 1.1491x over previous
//
#include <hip/hip_runtime.h>

#define NT 1024
#define RINGS 256

typedef _Float16 half8 __attribute__((ext_vector_type(8)));
typedef _Float16 half4 __attribute__((ext_vector_type(4)));
typedef float f32x4 __attribute__((ext_vector_type(4)));
typedef unsigned long long u64;
struct U2 { u64 a, b; };

__device__ __forceinline__ f32x4 MFMA(half8 a, half8 b, f32x4 c) {
  return __builtin_amdgcn_mfma_f32_16x16x32_f16(a, b, c, 0, 0, 0);
}
__device__ __forceinline__ float sigf(float x) {
  return __builtin_amdgcn_rcpf(1.0f + __expf(-x));
}
__device__ __forceinline__ float tanhf2(float x) {
  float ax = fabsf(x);
  float e = __expf(-2.0f * ax);
  float t = (1.0f - e) * __builtin_amdgcn_rcpf(1.0f + e);
  return copysignf(t, x);
}
__device__ __forceinline__ half8 cvt8(float4 c0, float4 c1) {
  half8 hv;
  hv[0] = (_Float16)c0.x; hv[1] = (_Float16)c0.y;
  hv[2] = (_Float16)c0.z; hv[3] = (_Float16)c0.w;
  hv[4] = (_Float16)c1.x; hv[5] = (_Float16)c1.y;
  hv[6] = (_Float16)c1.z; hv[7] = (_Float16)c1.w;
  return hv;
}
__device__ __forceinline__ half8 ldring(const _Float16* p) {
  const u64* q = (const u64*)p;
  U2 uu;
  uu.a = __hip_atomic_load(q, __ATOMIC_RELAXED, __HIP_MEMORY_SCOPE_AGENT);
  uu.b = __hip_atomic_load(q + 1, __ATOMIC_RELAXED, __HIP_MEMORY_SCOPE_AGENT);
  return __builtin_bit_cast(half8, uu);
}
__device__ __forceinline__ unsigned wpoll(unsigned* p, unsigned tgt,
                                          unsigned cached, int l) {
  unsigned c = cached;
  while (c < tgt) {
    unsigned pv = 0;
    if (l == 0)
      pv = __hip_atomic_load(p, __ATOMIC_ACQUIRE, __HIP_MEMORY_SCOPE_AGENT);
    c = (unsigned)__builtin_amdgcn_readfirstlane((int)pv);
    if (c < tgt) __builtin_amdgcn_s_sleep(2);
  }
  return c;
}

// Repack x [B,T,64] f32 -> f16 B-fragments Xf[g][t][kt][lane][8]
// k-perm within tile: kk(lane,j) = (j>>2)*16 + (lane>>4)*4 + (j&3)
__global__ __launch_bounds__(256) void prep_x(const float* __restrict__ x,
                                              _Float16* __restrict__ Xf) {
  int t0 = blockIdx.x * 256 + threadIdx.x;
  int l = t0 & 63;
  int fid = t0 >> 6;                  // ((g*NT + t)*2 + kt)
  int kt = fid & 1;
  int t = (fid >> 1) & (NT - 1);
  int g = fid >> 11;
  int bt = g * 16 + (l & 15);
  int kb = kt * 32 + (l >> 4) * 4;
  const float* src = x + ((size_t)bt * NT + (size_t)t) * 64 + kb;
  float4 v0 = *(const float4*)src;
  float4 v1 = *(const float4*)(src + 16);
  *(half8*)(Xf + (size_t)fid * 512 + l * 8) = cvt8(v0, v1);
}

// 16 blocks x 512 threads. Blocks 0-7: layer-0 producer for batch group g.
// Blocks 8-15: layer-1 + FC consumer. Producer uses RAW barriers (lgkm only)
// so agent-scope ring stores stay in flight; it drains vmcnt + publishes prog
// only every 32 steps (store-ack amortized ~80cyc/step). Consumer: cached
// flag polls, depth-2 ring prefetch across raw barriers.
__global__ __launch_bounds__(512, 1) void lstm_main(
    const float* __restrict__ wih0, const float* __restrict__ whh0,
    const float* __restrict__ wih1, const float* __restrict__ whh1,
    const float* __restrict__ bih, const float* __restrict__ bhh,
    const float* __restrict__ fcw, const float* __restrict__ fcb,
    const _Float16* __restrict__ Xf, _Float16* __restrict__ ringH0,
    unsigned* __restrict__ flags, float* __restrict__ out) {
  const int tid = threadIdx.x;
  const int w = tid >> 6, l = tid & 63;
  const int n = l & 15, lg = l >> 4;
  const bool producer = blockIdx.x < 8;
  const int g = blockIdx.x & 7;

  __shared__ _Float16 hfr[2][4][64][8];   // own-layer h frag ring (8 KB)
  __shared__ _Float16 fcl[4][4][64][8];   // FC A-frags per FC wave (16 KB)

  _Float16* ringG = ringH0 + (size_t)g * RINGS * 2048;
  unsigned* prog = flags + g * 16;        // producer progress
  unsigned* cons = flags + (8 + g) * 16;  // consumer progress
  const half8 hz = {0, 0, 0, 0, 0, 0, 0, 0};

  if (producer) {
    // ---- layer-0: Z = [x(64); h0(128)], 6 K-tiles ----
    half8 A[4][6];
    f32x4 bias[4];
#pragma unroll
    for (int q = 0; q < 4; ++q) {
      int row = (w + 8 * q) * 16 + n;
#pragma unroll
      for (int kt = 0; kt < 2; ++kt) {
        const float* wp = wih0 + (size_t)row * 64 + kt * 32 + lg * 4;
        A[q][kt] = cvt8(*(const float4*)wp, *(const float4*)(wp + 16));
      }
#pragma unroll
      for (int kt = 0; kt < 4; ++kt) {
        const float* wp = whh0 + (size_t)row * 128 + kt * 32 + lg * 4;
        A[q][2 + kt] = cvt8(*(const float4*)wp, *(const float4*)(wp + 16));
      }
      int rb = (w + 8 * q) * 16 + lg * 4;
      f32x4 bv;
#pragma unroll
      for (int r = 0; r < 4; ++r) bv[r] = bih[rb + r] + bhh[rb + r];
      bias[q] = bv;
    }
    if (tid < 256) ((half8*)&hfr[1][0][0][0])[tid] = hz;  // h0[-1]=0
    const _Float16* XfG = Xf + (size_t)g * NT * 1024;
    half8 x0 = *(const half8*)(XfG + l * 8);
    half8 x1 = *(const half8*)(XfG + 512 + l * 8);
    f32x4 cst = {0.f, 0.f, 0.f, 0.f};
    unsigned Cc = 0;
    __syncthreads();
    for (int s = 0; s < NT; ++s) {
      half8 xn0, xn1;
      if (s + 1 < NT) {
        const _Float16* p = XfG + (size_t)(s + 1) * 1024 + l * 8;
        xn0 = *(const half8*)p;
        xn1 = *(const half8*)(p + 512);
      }
      if (s >= 224 && (s & 31) == 0)  // ring backpressure (192-slot lead cap)
        Cc = wpoll(cons, (unsigned)(s - 192), Cc, l);
      const int rdk = (s + 1) & 1;
      half8 b2 = *(const half8*)&hfr[rdk][0][l][0];
      half8 b3 = *(const half8*)&hfr[rdk][1][l][0];
      half8 b4 = *(const half8*)&hfr[rdk][2][l][0];
      half8 b5 = *(const half8*)&hfr[rdk][3][l][0];
      f32x4 acc0 = bias[0], acc1 = bias[1], acc2 = bias[2], acc3 = bias[3];
      acc0 = MFMA(A[0][0], x0, acc0); acc1 = MFMA(A[1][0], x0, acc1);
      acc2 = MFMA(A[2][0], x0, acc2); acc3 = MFMA(A[3][0], x0, acc3);
      acc0 = MFMA(A[0][1], x1, acc0); acc1 = MFMA(A[1][1], x1, acc1);
      acc2 = MFMA(A[2][1], x1, acc2); acc3 = MFMA(A[3][1], x1, acc3);
      acc0 = MFMA(A[0][2], b2, acc0); acc1 = MFMA(A[1][2], b2, acc1);
      acc2 = MFMA(A[2][2], b2, acc2); acc3 = MFMA(A[3][2], b2, acc3);
      acc0 = MFMA(A[0][3], b3, acc0); acc1 = MFMA(A[1][3], b3, acc1);
      acc2 = MFMA(A[2][3], b3, acc2); acc3 = MFMA(A[3][3], b3, acc3);
      acc0 = MFMA(A[0][4], b4, acc0); acc1 = MFMA(A[1][4], b4, acc1);
      acc2 = MFMA(A[2][4], b4, acc2); acc3 = MFMA(A[3][4], b4, acc3);
      acc0 = MFMA(A[0][5], b5, acc0); acc1 = MFMA(A[1][5], b5, acc1);
      acc2 = MFMA(A[2][5], b5, acc2); acc3 = MFMA(A[3][5], b5, acc3);
      half4 hh;
#pragma unroll
      for (int r = 0; r < 4; ++r) {
        float iv = sigf(acc0[r]), fv = sigf(acc1[r]);
        float gv = tanhf2(acc2[r]), ov = sigf(acc3[r]);
        cst[r] = fv * cst[r] + iv * gv;
        hh[r] = (_Float16)(ov * tanhf2(cst[r]));
      }
      *(half4*)&hfr[s & 1][w >> 1][l][(w & 1) << 2] = hh;
      {  // ring store stays IN FLIGHT across the raw barrier (no drain)
        u64 uh = __builtin_bit_cast(u64, hh);
        __hip_atomic_store(
            (u64*)(ringG + (size_t)(s & (RINGS - 1)) * 2048 +
                   (w >> 1) * 512 + l * 8 + (w & 1) * 4),
            uh, __ATOMIC_RELAXED, __HIP_MEMORY_SCOPE_AGENT);
      }
      asm volatile("s_waitcnt lgkmcnt(0)" ::: "memory");
      __builtin_amdgcn_sched_barrier(0);
      __builtin_amdgcn_s_barrier();   // raw: vmcnt (ring stores) NOT drained
      __builtin_amdgcn_sched_barrier(0);
      if ((s & 31) == 31) {  // batched publish: drain all waves, then flag
        asm volatile("s_waitcnt vmcnt(0)" ::: "memory");
        __builtin_amdgcn_sched_barrier(0);
        __builtin_amdgcn_s_barrier();
        __builtin_amdgcn_sched_barrier(0);
        if (tid == 0)
          __hip_atomic_store(prog, (unsigned)(s + 1), __ATOMIC_RELEASE,
                             __HIP_MEMORY_SCOPE_AGENT);
      }
      x0 = xn0;
      x1 = xn1;
    }
  } else {
    // ---- layer-1 + FC: Z = [h0(128); h1(128)], 8 K-tiles ----
    half8 A[4][8];
    f32x4 bias[4], fcbv = {0.f, 0.f, 0.f, 0.f};
#pragma unroll
    for (int q = 0; q < 4; ++q) {
      int row = (w + 8 * q) * 16 + n;
#pragma unroll
      for (int kt = 0; kt < 4; ++kt) {
        const float* wp = wih1 + (size_t)row * 128 + kt * 32 + lg * 4;
        A[q][kt] = cvt8(*(const float4*)wp, *(const float4*)(wp + 16));
      }
#pragma unroll
      for (int kt = 0; kt < 4; ++kt) {
        const float* wp = whh1 + (size_t)row * 128 + kt * 32 + lg * 4;
        A[q][4 + kt] = cvt8(*(const float4*)wp, *(const float4*)(wp + 16));
      }
      int rb = (w + 8 * q) * 16 + lg * 4;
      f32x4 bv;
#pragma unroll
      for (int r = 0; r < 4; ++r)
        bv[r] = bih[512 + rb + r] + bhh[512 + rb + r];
      bias[q] = bv;
    }
    if (w < 4) {  // FC A-frags -> LDS (per FC wave w: out M-tile w)
      int frow = (w << 4) + n;
#pragma unroll
      for (int kt = 0; kt < 4; ++kt) {
        const float* wp = fcw + (size_t)frow * 128 + kt * 32 + lg * 4;
        *(half8*)&fcl[w][kt][l][0] =
            cvt8(*(const float4*)wp, *(const float4*)(wp + 16));
      }
      fcbv = *(const f32x4*)(fcb + (w << 4) + lg * 4);
    }
    if (tid < 256) ((half8*)&hfr[1][0][0][0])[tid] = hz;  // h1[-1]=0
    float* outG = out + (size_t)((g << 4) + n) * NT * 64 + (w << 4) + lg * 4;
    f32x4 cst = {0.f, 0.f, 0.f, 0.f};
    __syncthreads();
    unsigned Pc = wpoll(prog, 2u, 0u, l);
    half8 hA0 = ldring(ringG + l * 8);
    half8 hA1 = ldring(ringG + 512 + l * 8);
    half8 hA2 = ldring(ringG + 1024 + l * 8);
    half8 hA3 = ldring(ringG + 1536 + l * 8);
    const _Float16* rb1 = ringG + 2048 + l * 8;
    half8 hB0 = ldring(rb1);
    half8 hB1 = ldring(rb1 + 512);
    half8 hB2 = ldring(rb1 + 1024);
    half8 hB3 = ldring(rb1 + 1536);

#define CSTEP(T, C0, C1, C2, C3)                                               \
  {                                                                            \
    const int rdk_ = ((T) + 1) & 1;                                            \
    half8 b4 = *(const half8*)&hfr[rdk_][0][l][0];                             \
    half8 b5 = *(const half8*)&hfr[rdk_][1][l][0];                             \
    half8 b6 = *(const half8*)&hfr[rdk_][2][l][0];                             \
    half8 b7 = *(const half8*)&hfr[rdk_][3][l][0];                             \
    f32x4 acc0 = bias[0], acc1 = bias[1], acc2 = bias[2], acc3 = bias[3];      \
    acc0 = MFMA(A[0][0], C0, acc0); acc1 = MFMA(A[1][0], C0, acc1);            \
    acc2 = MFMA(A[2][0], C0, acc2); acc3 = MFMA(A[3][0], C0, acc3);            \
    acc0 = MFMA(A[0][1], C1, acc0); acc1 = MFMA(A[1][1], C1, acc1);            \
    acc2 = MFMA(A[2][1], C1, acc2); acc3 = MFMA(A[3][1], C1, acc3);            \
    acc0 = MFMA(A[0][2], C2, acc0); acc1 = MFMA(A[1][2], C2, acc1);            \
    acc2 = MFMA(A[2][2], C2, acc2); acc3 = MFMA(A[3][2], C2, acc3);            \
    acc0 = MFMA(A[0][3], C3, acc0); acc1 = MFMA(A[1][3], C3, acc1);            \
    acc2 = MFMA(A[2][3], C3, acc2); acc3 = MFMA(A[3][3], C3, acc3);            \
    if ((T) + 2 < NT) { /* reload CUR with h0[T+2]; flies across barriers */   \
      Pc = wpoll(prog, (unsigned)((T) + 3), Pc, l);                            \
      const _Float16* rb_ =                                                    \
          ringG + (size_t)(((T) + 2) & (RINGS - 1)) * 2048 + l * 8;            \
      C0 = ldring(rb_);        C1 = ldring(rb_ + 512);                         \
      C2 = ldring(rb_ + 1024); C3 = ldring(rb_ + 1536);                        \
    }                                                                          \
    acc0 = MFMA(A[0][4], b4, acc0); acc1 = MFMA(A[1][4], b4, acc1);            \
    acc2 = MFMA(A[2][4], b4, acc2); acc3 = MFMA(A[3][4], b4, acc3);            \
    acc0 = MFMA(A[0][5], b5, acc0); acc1 = MFMA(A[1][5], b5, acc1);            \
    acc2 = MFMA(A[2][5], b5, acc2); acc3 = MFMA(A[3][5], b5, acc3);            \
    acc0 = MFMA(A[0][6], b6, acc0); acc1 = MFMA(A[1][6], b6, acc1);            \
    acc2 = MFMA(A[2][6], b6, acc2); acc3 = MFMA(A[3][6], b6, acc3);            \
    acc0 = MFMA(A[0][7], b7, acc0); acc1 = MFMA(A[1][7], b7, acc1);            \
    acc2 = MFMA(A[2][7], b7, acc2); acc3 = MFMA(A[3][7], b7, acc3);            \
    if (w < 4) { /* FC of h1[T-1] on same operands */                          \
      half8 f0 = *(const half8*)&fcl[w][0][l][0];                              \
      half8 f1 = *(const half8*)&fcl[w][1][l][0];                              \
      half8 f2 = *(const half8*)&fcl[w][2][l][0];                              \
      half8 f3 = *(const half8*)&fcl[w][3][l][0];                              \
      f32x4 afc = fcbv;                                                        \
      afc = MFMA(f0, b4, afc); afc = MFMA(f1, b5, afc);                        \
      afc = MFMA(f2, b6, afc); afc = MFMA(f3, b7, afc);                        \
      if ((T) >= 1) *(f32x4*)(outG + (size_t)((T) - 1) * 64) = afc;            \
    }                                                                          \
    half4 hh;                                                                  \
    _Pragma("unroll")                                                          \
    for (int r = 0; r < 4; ++r) {                                              \
      float iv = sigf(acc0[r]), fv = sigf(acc1[r]);                            \
      float gv = tanhf2(acc2[r]), ov = sigf(acc3[r]);                          \
      cst[r] = fv * cst[r] + iv * gv;                                          \
      hh[r] = (_Float16)(ov * tanhf2(cst[r]));                                 \
    }                                                                          \
    *(half4*)&hfr[(T) & 1][w >> 1][l][(w & 1) << 2] = hh;                      \
    if (tid == 0 && ((T) & 31) == 0)                                           \
      __hip_atomic_store(cons, (unsigned)(T), __ATOMIC_RELAXED,                \
                         __HIP_MEMORY_SCOPE_AGENT);                            \
    asm volatile("s_waitcnt lgkmcnt(0)" ::: "memory");                         \
    __builtin_amdgcn_sched_barrier(0);                                         \
    __builtin_amdgcn_s_barrier(); /* raw: h0 prefetch stays in flight */       \
    __builtin_amdgcn_sched_barrier(0);                                         \
  }

    for (int t = 0; t < NT; t += 2) {
      CSTEP(t, hA0, hA1, hA2, hA3);
      CSTEP(t + 1, hB0, hB1, hB2, hB3);
    }
#undef CSTEP
    {  // epilogue: FC of h1[NT-1] -> out[NT-1]
      half8 b4 = *(const half8*)&hfr[(NT + 1) & 1][0][l][0];
      half8 b5 = *(const half8*)&hfr[(NT + 1) & 1][1][l][0];
      half8 b6 = *(const half8*)&hfr[(NT + 1) & 1][2][l][0];
      half8 b7 = *(const half8*)&hfr[(NT + 1) & 1][3][l][0];
      if (w < 4) {
        half8 f0 = *(const half8*)&fcl[w][0][l][0];
        half8 f1 = *(const half8*)&fcl[w][1][l][0];
        half8 f2 = *(const half8*)&fcl[w][2][l][0];
        half8 f3 = *(const half8*)&fcl[w][3][l][0];
        f32x4 afc = fcbv;
        afc = MFMA(f0, b4, afc); afc = MFMA(f1, b5, afc);
        afc = MFMA(f2, b6, afc); afc = MFMA(f3, b7, afc);
        *(f32x4*)(outG + (size_t)(NT - 1) * 64) = afc;
      }
    }
  }
}

extern "C" void kernel_launch(void* const* d_in, const int* in_sizes, int n_in,
                              void* d_out, int out_size, void* d_ws, size_t ws_size,
                              hipStream_t stream) {
  const float* x     = (const float*)d_in[0];
  const float* w_ih0 = (const float*)d_in[1];
  const float* w_hh0 = (const float*)d_in[2];
  const float* w_ih1 = (const float*)d_in[3];
  const float* w_hh1 = (const float*)d_in[4];
  const float* b_ih  = (const float*)d_in[5];
  const float* b_hh  = (const float*)d_in[6];
  const float* fc_w  = (const float*)d_in[7];
  const float* fc_b  = (const float*)d_in[8];

  _Float16* Xf   = (_Float16*)d_ws;                           // 16 MB
  _Float16* ring = (_Float16*)((char*)d_ws + (16u << 20));    // 8 MB
  unsigned* flags = (unsigned*)((char*)d_ws + (24u << 20));   // 4 KB

  hipMemsetAsync(flags, 0, 4096, stream);
  prep_x<<<4096, 256, 0, stream>>>(x, Xf);
  lstm_main<<<16, 512, 0, stream>>>(w_ih0, w_hh0, w_ih1, w_hh1, b_ih, b_hh,
                                    fc_w, fc_b, Xf, ring, flags,
                                    (float*)d_out);
}